// Round 6
// baseline (177.330 us; speedup 1.0000x reference)
//
#include <hip/hip_runtime.h>

#define XS 128
#define PLANE (XS * XS)            // 16384
#define X3 (XS * XS * XS)          // 2097152
#define ZC 4                       // owned planes per chunk
#define TPB 512                    // fused block size (8 waves)
#define SLOTS 8                    // prefetch slots: SLOTS*TPB = 4096 >= typical bin
#define QPT 8                      // float4 quads per thread = PLANE/4/TPB

// Raw barrier that drains LDS only (lgkmcnt), NOT vmcnt: lets prefetched
// global loads stay in flight across barriers (compiler's __syncthreads would
// force vmcnt(0) and kill the overlap).
__device__ __forceinline__ void bar_lgkm() {
    __builtin_amdgcn_sched_barrier(0);
    asm volatile("s_waitcnt lgkmcnt(0)" ::: "memory");
    __builtin_amdgcn_s_barrier();
    __builtin_amdgcn_sched_barrier(0);
}

// ---------------------------------------------------------------------------
// Pass 1: z-histogram, int4-vectorized (4 entries = 3 int4 per thread).
// ---------------------------------------------------------------------------
__global__ __launch_bounds__(256) void hist_kernel(
    const int* __restrict__ idx, int* __restrict__ hist, int N)
{
    __shared__ int lh[XS];
    for (int i = threadIdx.x; i < XS; i += 256) lh[i] = 0;
    __syncthreads();
    const int n4 = N >> 2;
    const int4* p = (const int4*)idx;
    for (int g = blockIdx.x * 256 + threadIdx.x; g < n4; g += gridDim.x * 256) {
        int4 A = p[3 * g], B = p[3 * g + 1], C = p[3 * g + 2];
        atomicAdd(&lh[A.x], 1); atomicAdd(&lh[A.w], 1);
        atomicAdd(&lh[B.z], 1); atomicAdd(&lh[C.y], 1);
    }
    for (int n = (n4 << 2) + blockIdx.x * 256 + threadIdx.x; n < N;
         n += gridDim.x * 256)
        atomicAdd(&lh[idx[3 * n]], 1);
    __syncthreads();
    for (int i = threadIdx.x; i < XS; i += 256)
        if (lh[i]) atomicAdd(&hist[i], lh[i]);
}

// ---------------------------------------------------------------------------
// Pass 2: parallel 128-bin exclusive scan (one block, 128 threads); also
// zeroes d_out so no separate memset dispatch is needed.
// ---------------------------------------------------------------------------
__global__ __launch_bounds__(128) void scan_kernel(
    const int* __restrict__ hist, int* __restrict__ base,
    int* __restrict__ cursor, float* __restrict__ out, int osz)
{
    __shared__ int sh[XS];
    const int t = threadIdx.x;
    const int h = hist[t];
    sh[t] = h;
    __syncthreads();
    for (int o = 1; o < XS; o <<= 1) {
        int v = (t >= o) ? sh[t - o] : 0;
        __syncthreads();
        sh[t] += v;
        __syncthreads();
    }
    const int excl = sh[t] - h;
    base[t] = excl; cursor[t] = excl;
    if (t < osz) out[t] = 0.f;
}

// ---------------------------------------------------------------------------
// Pass 3: reorder into per-z lists; 4 entries per thread held in registers
// across both phases (no global re-read). Entry: int2 {n, (y<<7)|x}.
// ---------------------------------------------------------------------------
__global__ __launch_bounds__(256) void reorder_kernel(
    const int* __restrict__ idx, int* __restrict__ cursor,
    int2* __restrict__ list, int N)
{
    __shared__ int lh[XS], lbase[XS];
    const int c0 = blockIdx.x * 1024;           // 256 threads * 4 entries
    int z[4], key[4], nn[4];
    int cntm = 0;

    for (int i = threadIdx.x; i < XS; i += 256) lh[i] = 0;

    if (c0 + 1024 <= N) {                       // fast vector path
        const int t = threadIdx.x;
        const int4* p = (const int4*)(idx + (size_t)c0 * 3);
        int4 A = p[3 * t], B = p[3 * t + 1], C = p[3 * t + 2];
        const int nb = c0 + 4 * t;
        z[0] = A.x; key[0] = (A.y << 7) | A.z; nn[0] = nb;
        z[1] = A.w; key[1] = (B.x << 7) | B.y; nn[1] = nb + 1;
        z[2] = B.z; key[2] = (B.w << 7) | C.x; nn[2] = nb + 2;
        z[3] = C.y; key[3] = (C.z << 7) | C.w; nn[3] = nb + 3;
        cntm = 4;
    } else {                                    // guarded tail block
        #pragma unroll
        for (int i = 0; i < 4; ++i) {
            const int n = c0 + 4 * threadIdx.x + i;
            if (n < N) {
                z[cntm]   = idx[3 * n];
                key[cntm] = (idx[3 * n + 1] << 7) | idx[3 * n + 2];
                nn[cntm]  = n;
                ++cntm;
            }
        }
    }
    __syncthreads();
    #pragma unroll
    for (int i = 0; i < 4; ++i)
        if (i < cntm) atomicAdd(&lh[z[i]], 1);
    __syncthreads();
    for (int i = threadIdx.x; i < XS; i += 256) {
        lbase[i] = lh[i] ? atomicAdd(&cursor[i], lh[i]) : 0;
        lh[i] = 0;
    }
    __syncthreads();
    #pragma unroll
    for (int i = 0; i < 4; ++i)
        if (i < cntm) {
            const int r = atomicAdd(&lh[z[i]], 1);
            list[lbase[z[i]] + r] = make_int2(nn[i], key[i]);
        }
}

// ---------------------------------------------------------------------------
// Pass 4 (fused): block = (b, z-chunk of ZC planes + halo). SINGLE 64 KB LDS
// plane buffer (-> 2 blocks/CU); previous plane carried in registers for the
// z-diff. Uniform predicated gather; (list,vals) for plane p+2 prefetched to
// registers during plane p+1's scatter; lgkm-only barriers keep those global
// loads in flight.
// ---------------------------------------------------------------------------
__global__ __launch_bounds__(TPB, 4) void fused_kernel(
    const int2* __restrict__ list, const int* __restrict__ base,
    const int* __restrict__ cnt, const float* __restrict__ vals,
    float* __restrict__ out, int N, int Btot)
{
    __shared__ float buf[PLANE];                // 64 KB
    __shared__ float rtv[TPB / 64], rms[TPB / 64];

    const int b   = blockIdx.x;
    const int z0  = blockIdx.y * ZC;
    const int tid = threadIdx.x;
    const float* vb = vals + (size_t)b * N;
    const int pmax = (z0 + ZC < XS) ? (z0 + ZC) : (XS - 1);

    int pos[SLOTS]; float val[SLOTS];
    int pc = 0, ps0 = 0;

    auto prefetch = [&](int zp) {
        ps0 = base[zp]; pc = cnt[zp];
        int2 e[SLOTS];
        #pragma unroll
        for (int i = 0; i < SLOTS; ++i) {
            const int ix = ps0 + tid + i * TPB;
            e[i] = list[ix < N ? ix : N - 1];
        }
        #pragma unroll
        for (int i = 0; i < SLOTS; ++i) { pos[i] = e[i].y; val[i] = vb[e[i].x]; }
    };
    auto scatter = [&]() {
        #pragma unroll
        for (int i = 0; i < SLOTS; ++i) {
            const float v = (tid + i * TPB < pc) ? val[i] : 0.f;
            atomicAdd(&buf[pos[i]], v);         // adds 0 when predicated off
        }
        for (int e = SLOTS * TPB + tid; e < pc; e += TPB) {   // rare overflow
            const int2 en = list[ps0 + e];
            atomicAdd(&buf[en.y], vb[en.x]);
        }
    };

    // prologue: build plane z0, prefetch z0+1
    prefetch(z0);
    #pragma unroll
    for (int i = 0; i < QPT; ++i)
        ((float4*)buf)[tid + i * TPB] = make_float4(0.f, 0.f, 0.f, 0.f);
    bar_lgkm();
    scatter();
    prefetch(z0 + 1);                           // z0+1 <= pmax always
    bar_lgkm();

    float4 prev[QPT];
    float tv = 0.f, ms = 0.f;

    for (int p = z0; p <= pmax; ++p) {
        float4 a[QPT];
        #pragma unroll
        for (int i = 0; i < QPT; ++i)
            a[i] = ((const float4*)buf)[tid + i * TPB];

        if (p > z0) {                           // z-diff pair (p-1, p)
            #pragma unroll
            for (int i = 0; i < QPT; ++i) {
                float d;
                d = a[i].x - prev[i].x; tv += fabsf(d); ms += d * d;
                d = a[i].y - prev[i].y; tv += fabsf(d); ms += d * d;
                d = a[i].z - prev[i].z; tv += fabsf(d); ms += d * d;
                d = a[i].w - prev[i].w; tv += fabsf(d); ms += d * d;
            }
        }
        if (p < z0 + ZC) {                      // owned plane: x/y diffs
            #pragma unroll
            for (int i = 0; i < QPT; ++i) {
                const int q = tid + i * TPB;
                const int qx = q & 31, y = q >> 5;
                float d;
                d = a[i].y - a[i].x; tv += fabsf(d); ms += d * d;
                d = a[i].z - a[i].y; tv += fabsf(d); ms += d * d;
                d = a[i].w - a[i].z; tv += fabsf(d); ms += d * d;
                if (qx < 31) {
                    d = buf[4 * q + 4] - a[i].w; tv += fabsf(d); ms += d * d;
                }
                if (y < XS - 1) {
                    const float4 u = ((const float4*)buf)[q + 32];
                    d = u.x - a[i].x; tv += fabsf(d); ms += d * d;
                    d = u.y - a[i].y; tv += fabsf(d); ms += d * d;
                    d = u.z - a[i].z; tv += fabsf(d); ms += d * d;
                    d = u.w - a[i].w; tv += fabsf(d); ms += d * d;
                }
            }
        }
        #pragma unroll
        for (int i = 0; i < QPT; ++i) prev[i] = a[i];

        if (p < pmax) {
            bar_lgkm();                         // all reads of buf done
            #pragma unroll
            for (int i = 0; i < QPT; ++i)
                ((float4*)buf)[tid + i * TPB] = make_float4(0.f, 0.f, 0.f, 0.f);
            bar_lgkm();                         // zero done
            scatter();                          // build plane p+1
            if (p + 2 <= pmax) prefetch(p + 2);
            bar_lgkm();                         // plane p+1 built
        }
    }

    for (int o = 32; o > 0; o >>= 1) {
        tv += __shfl_down(tv, o); ms += __shfl_down(ms, o);
    }
    if ((tid & 63) == 0) { rtv[tid >> 6] = tv; rms[tid >> 6] = ms; }
    __syncthreads();
    if (tid == 0) {
        float t = 0.f, m = 0.f;
        #pragma unroll
        for (int w = 0; w < TPB / 64; ++w) { t += rtv[w]; m += rms[w]; }
        atomicAdd(out + b,        t * (1.0f / (float)X3));
        atomicAdd(out + Btot + b, m * (1.0f / (float)(2 * XS * XS - 2 * XS)));
    }
}

extern "C" void kernel_launch(void* const* d_in, const int* in_sizes, int n_in,
                              void* d_out, int out_size, void* d_ws, size_t ws_size,
                              hipStream_t stream)
{
    const int*   indices = (const int*)d_in[0];
    const float* values  = (const float*)d_in[1];
    const int N = in_sizes[0] / 3;          // 500000
    const int B = in_sizes[1] / N;          // 16
    float* out = (float*)d_out;
    char*  ws  = (char*)d_ws;

    // ws layout: [list int2 * N][hist 128][base 128][cursor 128]
    int2* list   = (int2*)ws;
    int*  hist   = (int*)(ws + (size_t)N * sizeof(int2));
    int*  basep  = hist + XS;
    int*  cursor = basep + XS;

    hipMemsetAsync(hist, 0, XS * sizeof(int), stream);
    hist_kernel<<<256, 256, 0, stream>>>(indices, hist, N);
    scan_kernel<<<1, 128, 0, stream>>>(hist, basep, cursor, out, out_size);
    reorder_kernel<<<(N + 1023) / 1024, 256, 0, stream>>>(
        indices, cursor, list, N);
    fused_kernel<<<dim3(B, XS / ZC), TPB, 0, stream>>>(
        list, basep, hist, values, out, N, B);
}